// Round 7
// baseline (6943.057 us; speedup 1.0000x reference)
//
#include <hip/hip_runtime.h>
#include <hip/hip_bf16.h>
#include <stdint.h>

// RNN_75531294867647 on MI355X (gfx950)
// B=128 S=512 I=256 H=1024 O=256, fp32 in/out, LeakyReLU slope 0.01.
//
//   split:  x -> bf16 hi; Wi -> hi/lo; Wh -> WA hi (cols 0:1024), WB hi (cols 1024:2048)
//   gemm1:  xproj = LReLU(x @ Wi^T + bi) -> bf16 hi, layout [S][B][H]  (128MB)
//   recur:  h <- LReLU(xproj_t @ WA^T + bh + (h_hi + h_lo) @ WB^T), 512 steps.
//           64 persistent wgs, each TIME-MULTIPLEXES TWO independent batch
//           chains (groups q and q+4; 16 rows each) over the same 64-col WB
//           LDS slice: A.t, B.t, A.t+1, ... -> chain A's L3 sync round-trip
//           (store drain + flag propagate + poll) hides under chain B's
//           segment. Exchange h via L3-direct (sc0 sc1); per-slot flag stores;
//           per-wave min-of-4 poll with s_sleep backoff.
//   out:    out = h @ Wo^T + bo (f32 VALU, tiny)

#define LRELU_SLOPE 0.01f

typedef unsigned short u16;
typedef __bf16 bf16x8 __attribute__((ext_vector_type(8)));
typedef short  s16x8  __attribute__((ext_vector_type(8)));
typedef float  f32x4  __attribute__((ext_vector_type(4)));
typedef u16    u16x4  __attribute__((ext_vector_type(4)));
typedef uint32_t u32x4v __attribute__((ext_vector_type(4)));

__device__ __forceinline__ u16 f2bf(float f) {
  uint32_t u = __builtin_bit_cast(uint32_t, f);
  return (u16)((u + 0x7FFFu + ((u >> 16) & 1u)) >> 16);   // RNE
}
__device__ __forceinline__ float bf2f(u16 h) {
  uint32_t u = ((uint32_t)h) << 16;
  return __builtin_bit_cast(float, u);
}
__device__ __forceinline__ f32x4 mfma16(s16x8 a, s16x8 b, f32x4 c) {
  return __builtin_amdgcn_mfma_f32_16x16x32_bf16(
      __builtin_bit_cast(bf16x8, a), __builtin_bit_cast(bf16x8, b), c, 0, 0, 0);
}
__device__ __forceinline__ void gload_lds16(const void* g, void* l) {
  __builtin_amdgcn_global_load_lds(
      (const __attribute__((address_space(1))) void*)g,
      (__attribute__((address_space(3))) void*)l, 16, 0, 0);
}

// ---------------- fallback / split kernels -----------------------------------

__global__ void zero_out_k(float* __restrict__ out, int n) {
  int i = blockIdx.x * 256 + threadIdx.x;
  if (i < n) out[i] = 0.f;
}

__global__ void splitHi(const float* __restrict__ src, u16* __restrict__ hi, long n4) {
  long i = (long)blockIdx.x * 256 + threadIdx.x;
  if (i >= n4) return;
  float4 v = ((const float4*)src)[i];
  float a[4] = {v.x, v.y, v.z, v.w};
  u16x4 hv;
#pragma unroll
  for (int j = 0; j < 4; ++j) hv[j] = f2bf(a[j]);
  ((u16x4*)hi)[i] = hv;
}

__global__ void splitHiLo(const float* __restrict__ src, u16* __restrict__ hi,
                          u16* __restrict__ lo, long n4) {
  long i = (long)blockIdx.x * 256 + threadIdx.x;
  if (i >= n4) return;
  float4 v = ((const float4*)src)[i];
  float a[4] = {v.x, v.y, v.z, v.w};
  u16x4 hv, lv;
#pragma unroll
  for (int j = 0; j < 4; ++j) {
    u16 h = f2bf(a[j]);
    hv[j] = h;
    lv[j] = f2bf(a[j] - bf2f(h));
  }
  ((u16x4*)hi)[i] = hv;
  ((u16x4*)lo)[i] = lv;
}

// Wh [1024][2048] -> WAh = hi(cols 0:1024), WBh = hi(cols 1024:2048)
__global__ void split_wh(const float* __restrict__ Wh,
                         u16* __restrict__ WAh, u16* __restrict__ WBh) {
  long i4 = ((long)blockIdx.x * 256 + threadIdx.x) * 4;   // 1024*2048 elems
  int j = (int)(i4 >> 11), k2 = (int)(i4 & 2047);
  float4 v = *(const float4*)&Wh[i4];
  float a[4] = {v.x, v.y, v.z, v.w};
  u16x4 hv;
#pragma unroll
  for (int q = 0; q < 4; ++q) hv[q] = f2bf(a[q]);
  if (k2 < 1024) *(u16x4*)&WAh[(long)j * 1024 + k2]          = hv;
  else           *(u16x4*)&WBh[(long)j * 1024 + (k2 - 1024)] = hv;
}

// ---------------- gemm1: xproj = LReLU(x@Wi^T + bi) --------------------------

__global__ __launch_bounds__(256, 2)
void gemm_xproj(const u16* __restrict__ A, const u16* __restrict__ B0,
                const u16* __restrict__ B1, const float* __restrict__ bias,
                u16* __restrict__ outP) {
  __shared__ u16 sA[128 * 64], sB0[128 * 64], sB1[128 * 64];
  const int tid = threadIdx.x, wid = tid >> 6, lane = tid & 63;
  const int lrow = lane & 15, lgrp = lane >> 4;
  const int wm = wid >> 1, wn = wid & 1;
  const size_t m0 = (size_t)blockIdx.x * 128;
  const int n0 = blockIdx.y * 128;
  const int srow = tid >> 3, scol = (tid & 7) << 3;
  f32x4 acc[4][4] = {};

  for (int kt = 0; kt < 4; ++kt) {
    const int kph = kt << 6;
    __syncthreads();
#pragma unroll
    for (int sh = 0; sh < 4; ++sh) {
      const int r = sh * 32 + srow;
      gload_lds16(A  + (m0 + r) * 256 + kph + scol,          &sA [sh * 2048 + wid * 512]);
      gload_lds16(B0 + (size_t)(n0 + r) * 256 + kph + scol,  &sB0[sh * 2048 + wid * 512]);
      gload_lds16(B1 + (size_t)(n0 + r) * 256 + kph + scol,  &sB1[sh * 2048 + wid * 512]);
    }
    __syncthreads();
#pragma unroll
    for (int kk = 0; kk < 2; ++kk) {
      s16x8 bf0[4], bf1[4];
#pragma unroll
      for (int ni = 0; ni < 4; ++ni) {
        bf0[ni] = *(const s16x8*)&sB0[(wn * 64 + ni * 16 + lrow) * 64 + kk * 32 + lgrp * 8];
        bf1[ni] = *(const s16x8*)&sB1[(wn * 64 + ni * 16 + lrow) * 64 + kk * 32 + lgrp * 8];
      }
#pragma unroll
      for (int mi = 0; mi < 4; ++mi) {
        const s16x8 af = *(const s16x8*)&sA[(wm * 64 + mi * 16 + lrow) * 64 + kk * 32 + lgrp * 8];
#pragma unroll
        for (int ni = 0; ni < 4; ++ni) {
          acc[mi][ni] = mfma16(af, bf0[ni], acc[mi][ni]);
          acc[mi][ni] = mfma16(af, bf1[ni], acc[mi][ni]);
        }
      }
    }
  }
#pragma unroll
  for (int mi = 0; mi < 4; ++mi)
#pragma unroll
    for (int ni = 0; ni < 4; ++ni) {
      const int col = n0 + wn * 64 + ni * 16 + lrow;
      const float bv = bias[col];
#pragma unroll
      for (int r = 0; r < 4; ++r) {
        const size_t row = m0 + wm * 64 + mi * 16 + lgrp * 4 + r;
        float v = acc[mi][ni][r] + bv;
        v = (v >= 0.f) ? v : LRELU_SLOPE * v;
        const size_t b = row >> 9, s = row & 511;
        outP[(s * 128 + b) * 1024 + col] = f2bf(v);
      }
    }
}

// ---------------- recurrence -------------------------------------------------
// grid 64, 256 thr, 1 wg/CU. wg: q = wg>>4 (chain pair), jw = wg&15 (cols
// j0=64jw..+64). Chain A = group q (rows 16q..+16), chain B = group q+4.
// Waves = K-quarters kh. Flags: flags[g*64 + jw] (sc0sc1 store). Wave kh polls
// its 4 producers (slots 4kh..4kh+4) min-of-4 >= t, s_sleep backoff.
// WAR safety per chain (round-6 argument): 4 waves' polls cover all 16 slots;
// barrier A joins before any h-store of that chain.

__device__ __forceinline__ void segment(
    int t, s16x8 (&xbuf)[8], size_t rowoff, int b0, int j0, int jw,
    unsigned* __restrict__ flags, const unsigned* __restrict__ myfl,
    const u16* __restrict__ waL, const u16* __restrict__ xproj,
    const f32x4 bjA, const f32x4 bjB,
    u16* __restrict__ h0h, u16* __restrict__ h0l,
    u16* __restrict__ h1h, u16* __restrict__ h1l,
    u16* sWB, float (*sT)[16][68]) {
  const int tid = threadIdx.x, wid = tid >> 6, lane = tid & 63;
  const int lrow = lane & 15, lgrp = lane >> 4;
  const int kh = wid;
  const int er = tid >> 4, eplane = (tid & 15) >> 3, ecol = (tid & 7) * 8;

  const u16* hh = (t & 1) ? h1h : h0h;
  const u16* hl = (t & 1) ? h1l : h0l;
  u16* ohh = (t & 1) ? h0h : h1h;
  u16* ohl = (t & 1) ? h0l : h1l;
  const u16* hhp = hh + rowoff;
  const u16* hlp = hl + rowoff;

  // ---- phase U: xproj_t @ WA^T (pre-poll) ----
  f32x4 aU[4] = {{0.f,0.f,0.f,0.f},{0.f,0.f,0.f,0.f},{0.f,0.f,0.f,0.f},{0.f,0.f,0.f,0.f}};
#pragma unroll
  for (int n = 0; n < 4; ++n) {
#pragma unroll
    for (int kc = 0; kc < 8; ++kc) {
      const s16x8 wa = *(const s16x8*)(waL + ((size_t)n << 14) + kc * 32);
      aU[n] = mfma16(xbuf[kc], wa, aU[n]);
    }
  }

  // ---- refill xbuf for t+1 (plain cached loads; drained before next use) ----
  {
    const int tn = (t < 511) ? t + 1 : 511;
    const u16* xnext = xproj + (((size_t)tn) << 17) + rowoff;
#pragma unroll
    for (int kc = 0; kc < 8; ++kc)
      asm volatile("global_load_dwordx4 %0, %1, off"
                   : "=&v"(xbuf[kc]) : "v"(xnext + kc * 32));
  }

  // ---- per-wave poll: this wave's 4 producers reached step t ----
  if (t) {
    const unsigned tgt = (unsigned)t;
    u32x4v f;
    while (1) {
      asm volatile("global_load_dwordx4 %0, %1, off sc0 sc1\n\ts_waitcnt vmcnt(0)"
                   : "=&v"(f) : "v"(myfl) : "memory");
      const unsigned m01 = f[0] < f[1] ? f[0] : f[1];
      const unsigned m23 = f[2] < f[3] ? f[2] : f[3];
      if ((m01 < m23 ? m01 : m23) >= tgt) break;
      __builtin_amdgcn_s_sleep(1);
    }
  }
  __builtin_amdgcn_sched_barrier(0);

  // ---- phase H: (h_hi + h_lo) @ WB^T; 16 loads in flight, counted vmcnt ----
  s16x8 hb[8], lb[8];
#pragma unroll
  for (int kc = 0; kc < 8; ++kc) {
    asm volatile("global_load_dwordx4 %0, %1, off sc0 sc1"
                 : "=&v"(hb[kc]) : "v"(hhp + kc * 32));
    asm volatile("global_load_dwordx4 %0, %1, off sc0 sc1"
                 : "=&v"(lb[kc]) : "v"(hlp + kc * 32));
  }
#pragma unroll
  for (int kc = 0; kc < 8; ++kc) {
    switch (kc) {   // oldest-first retirement: chunk kc ready at vmcnt(14-2kc)
      case 0: asm volatile("s_waitcnt vmcnt(14)" ::: "memory"); break;
      case 1: asm volatile("s_waitcnt vmcnt(12)" ::: "memory"); break;
      case 2: asm volatile("s_waitcnt vmcnt(10)" ::: "memory"); break;
      case 3: asm volatile("s_waitcnt vmcnt(8)"  ::: "memory"); break;
      case 4: asm volatile("s_waitcnt vmcnt(6)"  ::: "memory"); break;
      case 5: asm volatile("s_waitcnt vmcnt(4)"  ::: "memory"); break;
      case 6: asm volatile("s_waitcnt vmcnt(2)"  ::: "memory"); break;
      default: asm volatile("s_waitcnt vmcnt(0)" ::: "memory"); break;
    }
    __builtin_amdgcn_sched_barrier(0);
    const int ka = kh * 32 + kc * 4 + lgrp;
#pragma unroll
    for (int n = 0; n < 4; ++n) {
      const int wr = n * 16 + lrow;
      const s16x8 wb = *(const s16x8*)&sWB[((size_t)wr << 10) + (size_t)((ka ^ (wr & 7)) << 3)];
      aU[n] = mfma16(hb[kc], wb, aU[n]);
      aU[n] = mfma16(lb[kc], wb, aU[n]);
    }
  }

  // ---- partials -> sT ----
#pragma unroll
  for (int n = 0; n < 4; ++n)
#pragma unroll
    for (int r = 0; r < 4; ++r)
      sT[kh][lgrp * 4 + r][n * 16 + lrow] = aU[n][r];
  __syncthreads();                      // barrier A: partials visible

  // ---- epilogue: reduce quarters, bias, LReLU, hi/lo, one 16B store ----
  {
    f32x4 vA = *(const f32x4*)&sT[0][er][ecol];
    vA += *(const f32x4*)&sT[1][er][ecol];
    vA += *(const f32x4*)&sT[2][er][ecol];
    vA += *(const f32x4*)&sT[3][er][ecol];
    vA += bjA;
    f32x4 vB = *(const f32x4*)&sT[0][er][ecol + 4];
    vB += *(const f32x4*)&sT[1][er][ecol + 4];
    vB += *(const f32x4*)&sT[2][er][ecol + 4];
    vB += *(const f32x4*)&sT[3][er][ecol + 4];
    vB += bjB;
    u16 o[8];
#pragma unroll
    for (int j = 0; j < 8; ++j) {
      float x = (j < 4) ? vA[j] : vB[j - 4];
      x = (x >= 0.f) ? x : LRELU_SLOPE * x;
      const u16 hB = f2bf(x);
      o[j] = eplane ? f2bf(x - bf2f(hB)) : hB;
    }
    u32x4v pk;
#pragma unroll
    for (int j = 0; j < 4; ++j)
      pk[j] = (unsigned)o[2 * j] | ((unsigned)o[2 * j + 1] << 16);
    u16* dst = (eplane ? ohl : ohh) + (((size_t)(b0 + er)) << 10) + j0 + ecol;
    asm volatile("global_store_dwordx4 %0, %1, off sc0 sc1"
                 :: "v"(dst), "v"(pk) : "memory");
  }
  asm volatile("s_waitcnt vmcnt(0)" ::: "memory");  // h stores + xbuf refill drained
  __syncthreads();                      // barrier B: wg-wide drain + sT WAR
  if (tid == 0)
    asm volatile("global_store_dword %0, %1, off sc0 sc1"
                 :: "v"(flags + jw), "v"((unsigned)(t + 1)) : "memory");
}

__global__ __launch_bounds__(256, 1)
void recur(const u16* __restrict__ WAh, const u16* __restrict__ WBh,
           const u16* __restrict__ xproj, const float* __restrict__ bh,
           u16* __restrict__ h0h, u16* __restrict__ h0l,
           u16* __restrict__ h1h, u16* __restrict__ h1l,
           unsigned* __restrict__ cnt) {
  __shared__ __align__(16) u16 sWB[64 * 1024];     // 128 KB
  __shared__ __align__(16) float sT[4][16][68];
  const int tid = threadIdx.x, wid = tid >> 6, lane = tid & 63;
  const int lrow = lane & 15, lgrp = lane >> 4;
  const int kh = wid;
  const int wg = blockIdx.x, q = wg >> 4, jw = wg & 15;
  const int j0 = jw * 64;
  const int b0A = q * 16, b0B = (q + 4) * 16;

  // WB slice rows j0..j0+64, 16B-granule XOR swizzle (slot = s ^ (r&7))
  for (int i = tid; i < 64 * 128; i += 256) {
    const int r = i >> 7, s = i & 127, sg = s ^ (r & 7);
    *(s16x8*)&sWB[(size_t)i * 8] = *(const s16x8*)&WBh[(((size_t)(j0 + r)) << 10) + sg * 8];
  }

  const int ecol = (tid & 7) * 8;
  const f32x4 bjA4 = *(const f32x4*)&bh[j0 + ecol];
  const f32x4 bjB4 = *(const f32x4*)&bh[j0 + ecol + 4];

  unsigned* flagsA = cnt + 64 + q * 64;        // groups 256B apart
  unsigned* flagsB = cnt + 64 + (q + 4) * 64;
  const unsigned* myflA = flagsA + kh * 4;
  const unsigned* myflB = flagsB + kh * 4;

  const size_t rowoffA = (((size_t)(b0A + lrow)) << 10) + kh * 256 + lgrp * 8;
  const size_t rowoffB = (((size_t)(b0B + lrow)) << 10) + kh * 256 + lgrp * 8;
  const u16* waL = WAh + (((size_t)(j0 + lrow)) << 10) + kh * 256 + lgrp * 8;

  // prologue: xbuf <- xproj_0 for both chains
  s16x8 xbufA[8], xbufB[8];
#pragma unroll
  for (int kc = 0; kc < 8; ++kc) {
    asm volatile("global_load_dwordx4 %0, %1, off"
                 : "=&v"(xbufA[kc]) : "v"(xproj + rowoffA + kc * 32));
    asm volatile("global_load_dwordx4 %0, %1, off"
                 : "=&v"(xbufB[kc]) : "v"(xproj + rowoffB + kc * 32));
  }
  asm volatile("s_waitcnt vmcnt(0)" ::: "memory");
  __syncthreads();                        // also covers LDS WB fill

  for (int t = 0; t < 512; ++t) {
    segment(t, xbufA, rowoffA, b0A, j0, jw, flagsA, myflA, waL, xproj,
            bjA4, bjB4, h0h, h0l, h1h, h1l, sWB, sT);
    segment(t, xbufB, rowoffB, b0B, j0, jw, flagsB, myflB, waL, xproj,
            bjA4, bjB4, h0h, h0l, h1h, h1l, sWB, sT);
  }
}

// ---------------- output GEMM (tiny, f32 VALU) -------------------------------

__global__ __launch_bounds__(256)
void out_gemm(const u16* __restrict__ hh, const u16* __restrict__ hl,
              const float* __restrict__ Wo, const float* __restrict__ bo,
              float* __restrict__ out) {
  __shared__ float hrow[1024];
  const int b = blockIdx.x, tid = threadIdx.x;
  for (int k = tid; k < 1024; k += 256)
    hrow[k] = bf2f(hh[((size_t)b << 10) + k]) + bf2f(hl[((size_t)b << 10) + k]);
  __syncthreads();
  const float* wo = Wo + (size_t)tid * 1024;
  float s0 = 0.f, s1 = 0.f, s2 = 0.f, s3 = 0.f;
  for (int k = 0; k < 1024; k += 4) {
    s0 = fmaf(wo[k + 0], hrow[k + 0], s0);
    s1 = fmaf(wo[k + 1], hrow[k + 1], s1);
    s2 = fmaf(wo[k + 2], hrow[k + 2], s2);
    s3 = fmaf(wo[k + 3], hrow[k + 3], s3);
  }
  out[(size_t)b * 256 + tid] = s0 + s1 + s2 + s3 + bo[tid];
}

// ---------------- launch ------------------------------------------------------

extern "C" void kernel_launch(void* const* d_in, const int* in_sizes, int n_in,
                              void* d_out, int out_size, void* d_ws, size_t ws_size,
                              hipStream_t stream) {
  const float* x  = (const float*)d_in[0];
  const float* Wi = (const float*)d_in[1];
  const float* bi = (const float*)d_in[2];
  const float* Wh = (const float*)d_in[3];
  const float* bh = (const float*)d_in[4];
  const float* Wo = (const float*)d_in[5];
  const float* bo = (const float*)d_in[6];

  char* w = (char*)d_ws;
  size_t off = 0;
  auto alloc = [&](size_t bytes) -> void* {
    void* p = w + off;
    off = (off + bytes + 255) & ~(size_t)255;
    return p;
  };
  u16* xh  = (u16*)alloc(33554432ull);    // x hi          [65536,256]
  u16* ph  = (u16*)alloc(134217728ull);   // xproj hi      [512][128][1024]
  u16* Wih = (u16*)alloc(524288ull);
  u16* Wil = (u16*)alloc(524288ull);
  u16* WAh = (u16*)alloc(2097152ull);     // Wh[:, :1024] hi
  u16* WBh = (u16*)alloc(2097152ull);     // Wh[:, 1024:] hi
  u16* h0h = (u16*)alloc(262144ull);
  u16* h0l = (u16*)alloc(262144ull);
  u16* h1h = (u16*)alloc(262144ull);
  u16* h1l = (u16*)alloc(262144ull);
  unsigned* cnt = (unsigned*)alloc(16384ull);
  const size_t needed = off;              // ~174 MB

  if (ws_size < needed) {                 // diagnostic fallback
    zero_out_k<<<(out_size + 255) / 256, 256, 0, stream>>>((float*)d_out, out_size);
    return;
  }

  hipMemsetAsync(cnt, 0, 16384, stream);
  hipMemsetAsync(h0h, 0, 262144, stream); // h_0 = 0
  hipMemsetAsync(h0l, 0, 262144, stream);

  splitHi  <<<16384, 256, 0, stream>>>(x, xh, 4194304);
  splitHiLo<<<256,   256, 0, stream>>>(Wi, Wih, Wil, 65536);
  split_wh <<<2048,  256, 0, stream>>>(Wh, WAh, WBh);

  gemm_xproj<<<dim3(512, 8), 256, 0, stream>>>(xh, Wih, Wil, bi, ph);

  recur<<<64, 256, 0, stream>>>(WAh, WBh, ph, bh, h0h, h0l, h1h, h1l, cnt);
  out_gemm<<<128, 256, 0, stream>>>(h0h, h0l, Wo, bo, (float*)d_out);
}

// Round 9
// 2427.682 us; speedup vs baseline: 2.8600x; 2.8600x over previous
//
#include <hip/hip_runtime.h>
#include <hip/hip_bf16.h>
#include <stdint.h>

// RNN_75531294867647 on MI355X (gfx950)
// B=128 S=512 I=256 H=1024 O=256, fp32 in/out, LeakyReLU slope 0.01.
//
//   split:  x -> bf16 hi; Wi -> hi/lo; Wh -> WA hi (cols 0:1024), WB hi (cols 1024:2048)
//   gemm1:  xproj = LReLU(x @ Wi^T + bi) -> bf16 hi, layout [S][B][H]  (128MB)
//   recur:  h <- LReLU(xproj_t @ WA^T + bh + (h_hi + h_lo) @ WB^T), 512 steps.
//           ROUND-4 PROTOCOL (best proven): grid 128, 1 wg/CU, 8 groups
//           (g = wg&7) x 16 j-wgs (64 cols); waves = K-quarters; WB slice in
//           LDS (128KB, XOR-swizzled); WA from L2; xproj register-prefetched;
//           h exchange L3-direct (sc0 sc1); per-group arrival counter + tid0
//           poll with s_sleep(1). Deltas vs round 4 (protocol-neutral):
//           (1) arrival striped over 4 counters (jw&3) -> 4x less RMW
//               serialization; poll = one dwordx4, min-of-4 >= 4t.
//           (2) epilogue emits one 16B store/thread (was 8x2B).
//   out:    out = h @ Wo^T + bo (f32 VALU, tiny)

#define LRELU_SLOPE 0.01f

typedef unsigned short u16;
typedef __bf16 bf16x8 __attribute__((ext_vector_type(8)));
typedef short  s16x8  __attribute__((ext_vector_type(8)));
typedef float  f32x4  __attribute__((ext_vector_type(4)));
typedef u16    u16x4  __attribute__((ext_vector_type(4)));
typedef uint32_t u32x4v __attribute__((ext_vector_type(4)));

__device__ __forceinline__ u16 f2bf(float f) {
  uint32_t u = __builtin_bit_cast(uint32_t, f);
  return (u16)((u + 0x7FFFu + ((u >> 16) & 1u)) >> 16);   // RNE
}
__device__ __forceinline__ float bf2f(u16 h) {
  uint32_t u = ((uint32_t)h) << 16;
  return __builtin_bit_cast(float, u);
}
__device__ __forceinline__ f32x4 mfma16(s16x8 a, s16x8 b, f32x4 c) {
  return __builtin_amdgcn_mfma_f32_16x16x32_bf16(
      __builtin_bit_cast(bf16x8, a), __builtin_bit_cast(bf16x8, b), c, 0, 0, 0);
}
__device__ __forceinline__ void gload_lds16(const void* g, void* l) {
  __builtin_amdgcn_global_load_lds(
      (const __attribute__((address_space(1))) void*)g,
      (__attribute__((address_space(3))) void*)l, 16, 0, 0);
}

// ---------------- fallback / split kernels -----------------------------------

__global__ void zero_out_k(float* __restrict__ out, int n) {
  int i = blockIdx.x * 256 + threadIdx.x;
  if (i < n) out[i] = 0.f;
}

__global__ void splitHi(const float* __restrict__ src, u16* __restrict__ hi, long n4) {
  long i = (long)blockIdx.x * 256 + threadIdx.x;
  if (i >= n4) return;
  float4 v = ((const float4*)src)[i];
  float a[4] = {v.x, v.y, v.z, v.w};
  u16x4 hv;
#pragma unroll
  for (int j = 0; j < 4; ++j) hv[j] = f2bf(a[j]);
  ((u16x4*)hi)[i] = hv;
}

__global__ void splitHiLo(const float* __restrict__ src, u16* __restrict__ hi,
                          u16* __restrict__ lo, long n4) {
  long i = (long)blockIdx.x * 256 + threadIdx.x;
  if (i >= n4) return;
  float4 v = ((const float4*)src)[i];
  float a[4] = {v.x, v.y, v.z, v.w};
  u16x4 hv, lv;
#pragma unroll
  for (int j = 0; j < 4; ++j) {
    u16 h = f2bf(a[j]);
    hv[j] = h;
    lv[j] = f2bf(a[j] - bf2f(h));
  }
  ((u16x4*)hi)[i] = hv;
  ((u16x4*)lo)[i] = lv;
}

// Wh [1024][2048] -> WAh = hi(cols 0:1024), WBh = hi(cols 1024:2048)
__global__ void split_wh(const float* __restrict__ Wh,
                         u16* __restrict__ WAh, u16* __restrict__ WBh) {
  long i4 = ((long)blockIdx.x * 256 + threadIdx.x) * 4;   // 1024*2048 elems
  int j = (int)(i4 >> 11), k2 = (int)(i4 & 2047);
  float4 v = *(const float4*)&Wh[i4];
  float a[4] = {v.x, v.y, v.z, v.w};
  u16x4 hv;
#pragma unroll
  for (int q = 0; q < 4; ++q) hv[q] = f2bf(a[q]);
  if (k2 < 1024) *(u16x4*)&WAh[(long)j * 1024 + k2]          = hv;
  else           *(u16x4*)&WBh[(long)j * 1024 + (k2 - 1024)] = hv;
}

// ---------------- gemm1: xproj = LReLU(x@Wi^T + bi) --------------------------

__global__ __launch_bounds__(256, 2)
void gemm_xproj(const u16* __restrict__ A, const u16* __restrict__ B0,
                const u16* __restrict__ B1, const float* __restrict__ bias,
                u16* __restrict__ outP) {
  __shared__ u16 sA[128 * 64], sB0[128 * 64], sB1[128 * 64];
  const int tid = threadIdx.x, wid = tid >> 6, lane = tid & 63;
  const int lrow = lane & 15, lgrp = lane >> 4;
  const int wm = wid >> 1, wn = wid & 1;
  const size_t m0 = (size_t)blockIdx.x * 128;
  const int n0 = blockIdx.y * 128;
  const int srow = tid >> 3, scol = (tid & 7) << 3;
  f32x4 acc[4][4] = {};

  for (int kt = 0; kt < 4; ++kt) {
    const int kph = kt << 6;
    __syncthreads();
#pragma unroll
    for (int sh = 0; sh < 4; ++sh) {
      const int r = sh * 32 + srow;
      gload_lds16(A  + (m0 + r) * 256 + kph + scol,          &sA [sh * 2048 + wid * 512]);
      gload_lds16(B0 + (size_t)(n0 + r) * 256 + kph + scol,  &sB0[sh * 2048 + wid * 512]);
      gload_lds16(B1 + (size_t)(n0 + r) * 256 + kph + scol,  &sB1[sh * 2048 + wid * 512]);
    }
    __syncthreads();
#pragma unroll
    for (int kk = 0; kk < 2; ++kk) {
      s16x8 bf0[4], bf1[4];
#pragma unroll
      for (int ni = 0; ni < 4; ++ni) {
        bf0[ni] = *(const s16x8*)&sB0[(wn * 64 + ni * 16 + lrow) * 64 + kk * 32 + lgrp * 8];
        bf1[ni] = *(const s16x8*)&sB1[(wn * 64 + ni * 16 + lrow) * 64 + kk * 32 + lgrp * 8];
      }
#pragma unroll
      for (int mi = 0; mi < 4; ++mi) {
        const s16x8 af = *(const s16x8*)&sA[(wm * 64 + mi * 16 + lrow) * 64 + kk * 32 + lgrp * 8];
#pragma unroll
        for (int ni = 0; ni < 4; ++ni) {
          acc[mi][ni] = mfma16(af, bf0[ni], acc[mi][ni]);
          acc[mi][ni] = mfma16(af, bf1[ni], acc[mi][ni]);
        }
      }
    }
  }
#pragma unroll
  for (int mi = 0; mi < 4; ++mi)
#pragma unroll
    for (int ni = 0; ni < 4; ++ni) {
      const int col = n0 + wn * 64 + ni * 16 + lrow;
      const float bv = bias[col];
#pragma unroll
      for (int r = 0; r < 4; ++r) {
        const size_t row = m0 + wm * 64 + mi * 16 + lgrp * 4 + r;
        float v = acc[mi][ni][r] + bv;
        v = (v >= 0.f) ? v : LRELU_SLOPE * v;
        const size_t b = row >> 9, s = row & 511;
        outP[(s * 128 + b) * 1024 + col] = f2bf(v);
      }
    }
}

// ---------------- recurrence (round-4 protocol, striped arrivals) ------------
// grid 128, 256 thr, 1 wg/CU (145KB LDS). wg: g = wg&7 (rows b0=16g..+16),
// jw = wg>>3 (cols j0=64jw..+64). Waves = K-quarters kh.
// Arrival: atomic add to stripe cnt[64 + g*64 + (jw&3)] (4 wgs/stripe).
// Poll (tid0): one dwordx4 of the 4 stripes, min >= 4t, s_sleep(1) backoff.
// WAR safety: poll at step t guarantees all 16 wgs finished step t-1 (their
// reads of buf[(t-1)&1] are done) before this wg's step-t stores overwrite it.

__global__ __launch_bounds__(256, 1)
void recur(const u16* __restrict__ WAh, const u16* __restrict__ WBh,
           const u16* __restrict__ xproj, const float* __restrict__ bh,
           u16* __restrict__ h0h, u16* __restrict__ h0l,
           u16* __restrict__ h1h, u16* __restrict__ h1l,
           unsigned* __restrict__ cnt) {
  __shared__ __align__(16) u16 sWB[64 * 1024];     // 128 KB
  __shared__ __align__(16) float sT[4][16][68];    // padded for f32x4 reads
  const int tid = threadIdx.x, wid = tid >> 6, lane = tid & 63;
  const int lrow = lane & 15, lgrp = lane >> 4;
  const int kh = wid;                     // K-quarter
  const int wg = blockIdx.x, g = wg & 7, jw = wg >> 3;
  const int b0 = g * 16, j0 = jw * 64;

  // WB slice rows j0..j0+64, 16B-granule XOR swizzle (slot = s ^ (r&7))
  for (int i = tid; i < 64 * 128; i += 256) {
    const int r = i >> 7, s = i & 127, sg = s ^ (r & 7);
    *(s16x8*)&sWB[(size_t)i * 8] = *(const s16x8*)&WBh[(((size_t)(j0 + r)) << 10) + sg * 8];
  }

  // epilogue constants: thread -> (row er, plane, 8 cols at ecol) = 16B store
  const int er = tid >> 4;
  const int eplane = (tid & 15) >> 3;
  const int ecol = (tid & 7) * 8;
  const f32x4 bjA = *(const f32x4*)&bh[j0 + ecol];
  const f32x4 bjB = *(const f32x4*)&bh[j0 + ecol + 4];

  unsigned* stripes = cnt + 64 + g * 64;  // 4 stripe counters, one 16B line
  unsigned* mystripe = stripes + (jw & 3);

  const size_t rowoff = (((size_t)(b0 + lrow)) << 10) + kh * 256 + lgrp * 8;
  const u16* waL = WAh + (((size_t)(j0 + lrow)) << 10) + kh * 256 + lgrp * 8;

  // prologue: xbuf <- xproj_0
  s16x8 xbuf[8];
#pragma unroll
  for (int kc = 0; kc < 8; ++kc)
    asm volatile("global_load_dwordx4 %0, %1, off"
                 : "=&v"(xbuf[kc]) : "v"(xproj + rowoff + kc * 32));
  asm volatile("s_waitcnt vmcnt(0)" ::: "memory");
  __syncthreads();                        // also covers LDS WB fill

  for (int t = 0; t < 512; ++t) {
    const u16* hh = (t & 1) ? h1h : h0h;
    const u16* hl = (t & 1) ? h1l : h0l;
    u16* ohh = (t & 1) ? h0h : h1h;
    u16* ohl = (t & 1) ? h0l : h1l;
    const u16* hhp = hh + rowoff;
    const u16* hlp = hl + rowoff;

    // ---- phase U: xproj_t @ WA^T (pre-poll; WA slice L2-resident) ----
    f32x4 aU[4] = {{0.f,0.f,0.f,0.f},{0.f,0.f,0.f,0.f},{0.f,0.f,0.f,0.f},{0.f,0.f,0.f,0.f}};
#pragma unroll
    for (int n = 0; n < 4; ++n) {
#pragma unroll
      for (int kc = 0; kc < 8; ++kc) {
        const s16x8 wa = *(const s16x8*)(waL + ((size_t)n << 14) + kc * 32);
        aU[n] = mfma16(xbuf[kc], wa, aU[n]);
      }
    }

    // ---- refill xbuf for t+1 (plain cached loads; drained by epilogue) ----
    {
      const int tn = (t < 511) ? t + 1 : 511;
      const u16* xnext = xproj + (((size_t)tn) << 17) + rowoff;
#pragma unroll
      for (int kc = 0; kc < 8; ++kc)
        asm volatile("global_load_dwordx4 %0, %1, off"
                     : "=&v"(xbuf[kc]) : "v"(xnext + kc * 32));
    }

    // ---- spin: h_t ready when every stripe reached 4t ----
    if (t) {
      const unsigned target = (unsigned)t * 4u;
      u32x4v f;
      while (1) {
        asm volatile("global_load_dwordx4 %0, %1, off sc0 sc1\n\ts_waitcnt vmcnt(0)"
                     : "=&v"(f) : "v"(stripes) : "memory");
        const unsigned m01 = f[0] < f[1] ? f[0] : f[1];
        const unsigned m23 = f[2] < f[3] ? f[2] : f[3];
        if ((m01 < m23 ? m01 : m23) >= target) break;
        __builtin_amdgcn_s_sleep(1);
      }
    }
    __builtin_amdgcn_sched_barrier(0);

    // ---- phase H: (h_hi + h_lo) @ WB^T; 16 loads in flight, counted vmcnt ----
    s16x8 hb[8], lb[8];
#pragma unroll
    for (int kc = 0; kc < 8; ++kc) {
      asm volatile("global_load_dwordx4 %0, %1, off sc0 sc1"
                   : "=&v"(hb[kc]) : "v"(hhp + kc * 32));
      asm volatile("global_load_dwordx4 %0, %1, off sc0 sc1"
                   : "=&v"(lb[kc]) : "v"(hlp + kc * 32));
    }
#pragma unroll
    for (int kc = 0; kc < 8; ++kc) {
      switch (kc) {   // oldest-first retirement: chunk kc ready at vmcnt(14-2kc)
        case 0: asm volatile("s_waitcnt vmcnt(14)" ::: "memory"); break;
        case 1: asm volatile("s_waitcnt vmcnt(12)" ::: "memory"); break;
        case 2: asm volatile("s_waitcnt vmcnt(10)" ::: "memory"); break;
        case 3: asm volatile("s_waitcnt vmcnt(8)"  ::: "memory"); break;
        case 4: asm volatile("s_waitcnt vmcnt(6)"  ::: "memory"); break;
        case 5: asm volatile("s_waitcnt vmcnt(4)"  ::: "memory"); break;
        case 6: asm volatile("s_waitcnt vmcnt(2)"  ::: "memory"); break;
        default: asm volatile("s_waitcnt vmcnt(0)" ::: "memory"); break;
      }
      __builtin_amdgcn_sched_barrier(0);
      const int ka = kh * 32 + kc * 4 + lgrp;
#pragma unroll
      for (int n = 0; n < 4; ++n) {
        const int wr = n * 16 + lrow;
        const s16x8 wb = *(const s16x8*)&sWB[((size_t)wr << 10) + (size_t)((ka ^ (wr & 7)) << 3)];
        aU[n] = mfma16(hb[kc], wb, aU[n]);
        aU[n] = mfma16(lb[kc], wb, aU[n]);
      }
    }

    // ---- partials -> sT ----
#pragma unroll
    for (int n = 0; n < 4; ++n)
#pragma unroll
      for (int r = 0; r < 4; ++r)
        sT[kh][lgrp * 4 + r][n * 16 + lrow] = aU[n][r];
    __syncthreads();                      // barrier A: partials visible

    // ---- epilogue: reduce quarters, bias, LReLU, hi/lo, one 16B store ----
    {
      f32x4 vA = *(const f32x4*)&sT[0][er][ecol];
      vA += *(const f32x4*)&sT[1][er][ecol];
      vA += *(const f32x4*)&sT[2][er][ecol];
      vA += *(const f32x4*)&sT[3][er][ecol];
      vA += bjA;
      f32x4 vB = *(const f32x4*)&sT[0][er][ecol + 4];
      vB += *(const f32x4*)&sT[1][er][ecol + 4];
      vB += *(const f32x4*)&sT[2][er][ecol + 4];
      vB += *(const f32x4*)&sT[3][er][ecol + 4];
      vB += bjB;
      u16 o[8];
#pragma unroll
      for (int j = 0; j < 8; ++j) {
        float x = (j < 4) ? vA[j] : vB[j - 4];
        x = (x >= 0.f) ? x : LRELU_SLOPE * x;
        const u16 hB = f2bf(x);
        o[j] = eplane ? f2bf(x - bf2f(hB)) : hB;
      }
      u32x4v pk;
#pragma unroll
      for (int j = 0; j < 4; ++j)
        pk[j] = (unsigned)o[2 * j] | ((unsigned)o[2 * j + 1] << 16);
      u16* dst = (eplane ? ohl : ohh) + (((size_t)(b0 + er)) << 10) + j0 + ecol;
      asm volatile("global_store_dwordx4 %0, %1, off sc0 sc1"
                   :: "v"(dst), "v"(pk) : "memory");
    }
    asm volatile("s_waitcnt vmcnt(0)" ::: "memory");  // h store + refill drained
    __syncthreads();                      // barrier B: wg-wide drain + sT WAR
    if (tid == 0)
      __hip_atomic_fetch_add(mystripe, 1u, __ATOMIC_RELAXED, __HIP_MEMORY_SCOPE_AGENT);
  }
}

// ---------------- output GEMM (tiny, f32 VALU) -------------------------------

__global__ __launch_bounds__(256)
void out_gemm(const u16* __restrict__ hh, const u16* __restrict__ hl,
              const float* __restrict__ Wo, const float* __restrict__ bo,
              float* __restrict__ out) {
  __shared__ float hrow[1024];
  const int b = blockIdx.x, tid = threadIdx.x;
  for (int k = tid; k < 1024; k += 256)
    hrow[k] = bf2f(hh[((size_t)b << 10) + k]) + bf2f(hl[((size_t)b << 10) + k]);
  __syncthreads();
  const float* wo = Wo + (size_t)tid * 1024;
  float s0 = 0.f, s1 = 0.f, s2 = 0.f, s3 = 0.f;
  for (int k = 0; k < 1024; k += 4) {
    s0 = fmaf(wo[k + 0], hrow[k + 0], s0);
    s1 = fmaf(wo[k + 1], hrow[k + 1], s1);
    s2 = fmaf(wo[k + 2], hrow[k + 2], s2);
    s3 = fmaf(wo[k + 3], hrow[k + 3], s3);
  }
  out[(size_t)b * 256 + tid] = s0 + s1 + s2 + s3 + bo[tid];
}

// ---------------- launch ------------------------------------------------------

extern "C" void kernel_launch(void* const* d_in, const int* in_sizes, int n_in,
                              void* d_out, int out_size, void* d_ws, size_t ws_size,
                              hipStream_t stream) {
  const float* x  = (const float*)d_in[0];
  const float* Wi = (const float*)d_in[1];
  const float* bi = (const float*)d_in[2];
  const float* Wh = (const float*)d_in[3];
  const float* bh = (const float*)d_in[4];
  const float* Wo = (const float*)d_in[5];
  const float* bo = (const float*)d_in[6];

  char* w = (char*)d_ws;
  size_t off = 0;
  auto alloc = [&](size_t bytes) -> void* {
    void* p = w + off;
    off = (off + bytes + 255) & ~(size_t)255;
    return p;
  };
  u16* xh  = (u16*)alloc(33554432ull);    // x hi          [65536,256]
  u16* ph  = (u16*)alloc(134217728ull);   // xproj hi      [512][128][1024]
  u16* Wih = (u16*)alloc(524288ull);
  u16* Wil = (u16*)alloc(524288ull);
  u16* WAh = (u16*)alloc(2097152ull);     // Wh[:, :1024] hi
  u16* WBh = (u16*)alloc(2097152ull);     // Wh[:, 1024:] hi
  u16* h0h = (u16*)alloc(262144ull);
  u16* h0l = (u16*)alloc(262144ull);
  u16* h1h = (u16*)alloc(262144ull);
  u16* h1l = (u16*)alloc(262144ull);
  unsigned* cnt = (unsigned*)alloc(16384ull);
  const size_t needed = off;              // ~174 MB

  if (ws_size < needed) {                 // diagnostic fallback
    zero_out_k<<<(out_size + 255) / 256, 256, 0, stream>>>((float*)d_out, out_size);
    return;
  }

  hipMemsetAsync(cnt, 0, 16384, stream);
  hipMemsetAsync(h0h, 0, 262144, stream); // h_0 = 0
  hipMemsetAsync(h0l, 0, 262144, stream);

  splitHi  <<<16384, 256, 0, stream>>>(x, xh, 4194304);
  splitHiLo<<<256,   256, 0, stream>>>(Wi, Wih, Wil, 65536);
  split_wh <<<2048,  256, 0, stream>>>(Wh, WAh, WBh);

  gemm_xproj<<<dim3(512, 8), 256, 0, stream>>>(xh, Wih, Wil, bi, ph);

  recur<<<128, 256, 0, stream>>>(WAh, WBh, ph, bh, h0h, h0l, h1h, h1l, cnt);
  out_gemm<<<128, 256, 0, stream>>>(h0h, h0l, Wo, bo, (float*)d_out);
}